// Round 9
// baseline (92.297 us; speedup 1.0000x reference)
//
#include <hip/hip_runtime.h>

// SparseConv1D on MI355X, round 8.
// out[b,o,l] = sum_{t,i} W[o,i,t] * x[b,i,l+tap_t] = 32 shifted GEMMs (MFMA 16x16x32 bf16).
// R8 = consolidation of every measured win:
//  - 2 blocks/CU (grid 512, 256-thr blocks): one block's barrier drain is covered by the
//    other block's MFMAs (R2-era TLP, lost in R6/R7's 1-block/CU).
//  - FULL-K waves (m4n2c2, 64o x 32l x 64i): no k-split -> epilogue reduction gone
//    (2 barriers + 32KB LDS round-trip saved), acc = 32 VGPRs, all waves store.
//  - W stays register-only (R7): frag-major global loads, 2-deep dbuf, 1 tap ahead.
//  - Ring 512 rows x 128B = 64KB; tap chunks sized by gap ({0},{1},{2,3},{4-7},{8-15},
//    {16-23},{24-31}): 7 barriers; max live span 390 < 512 rows (WAR-safe, verified
//    per chunk); delta staged one chunk ahead.

#define B_    16
#define CIN   64
#define COUT  64
#define LEN   4096
#define PAD_LO 512
#define PAD_HI 256
#define LPAD  (LEN + PAD_LO + PAD_HI)   // 4864
#define NTAP  32

typedef float f32x4 __attribute__((ext_vector_type(4)));
typedef short bf16x8_s __attribute__((ext_vector_type(8)));
typedef __bf16 bf16x8_b __attribute__((ext_vector_type(8)));
typedef unsigned short u16x8 __attribute__((ext_vector_type(8)));

template <typename V>
static __device__ inline auto mfma_16x16x32_bf16(V a, V b, f32x4 c, int)
    -> decltype(__builtin_amdgcn_mfma_f32_16x16x32_bf16(a, b, c, 0, 0, 0)) {
  return __builtin_amdgcn_mfma_f32_16x16x32_bf16(a, b, c, 0, 0, 0);
}
template <typename V>
static __device__ inline f32x4 mfma_16x16x32_bf16(V a, V b, f32x4 c, long) {
  return __builtin_amdgcn_mfma_f32_16x16x32_bf16(
      __builtin_bit_cast(bf16x8_b, a), __builtin_bit_cast(bf16x8_b, b), c, 0, 0, 0);
}

static __device__ inline unsigned short f32_to_bf16_rne(float f) {
  unsigned int u = __builtin_bit_cast(unsigned int, f);
  u += 0x7fffu + ((u >> 16) & 1u);
  return (unsigned short)(u >> 16);
}

// async 16B/lane global->LDS; lds dest is the wave-uniform base (HW adds lane*16)
static __device__ inline void async_copy16(const void* g, void* l) {
  __builtin_amdgcn_global_load_lds((const __attribute__((address_space(1))) unsigned int*)g,
                                   (__attribute__((address_space(3))) unsigned int*)l, 16, 0, 0);
}

// ---- fused prep: x[b][i][l] f32 -> Xp[b][lp][i] bf16 (padded); pad-blocks also do
// ---- w[o][i][t] f32 -> Wf[t][c][m][lane][8] bf16 (frag-major, 8KB/tap)
__global__ __launch_bounds__(256) void prep_xw(const float* __restrict__ x,
                                               const float* __restrict__ w,
                                               unsigned short* __restrict__ xp,
                                               unsigned short* __restrict__ wf) {
  __shared__ float tile[64][65];
  const int b = blockIdx.y;
  const int lp0 = blockIdx.x * 64;
  const int tid = threadIdx.x;
  const bool data = (lp0 >= PAD_LO) && (lp0 < PAD_LO + LEN);
  if (data) {
    const int l0 = lp0 - PAD_LO;
#pragma unroll
    for (int it = 0; it < 4; ++it) {
      const int pidx = it * 256 + tid;
      const int il = pidx >> 4;
      const int lq = (pidx & 15) * 4;
      const float4 v = *(const float4*)&x[(size_t)(b * CIN + il) * LEN + l0 + lq];
      tile[lq + 0][il] = v.x;
      tile[lq + 1][il] = v.y;
      tile[lq + 2][il] = v.z;
      tile[lq + 3][il] = v.w;
    }
  } else if (lp0 < PAD_LO) {
    // pad block: also transpose a 1/128 slice of W (16 b * 8 x-blocks = 128 slices)
    const int base = (b * 8 + blockIdx.x) * 1024;
#pragma unroll
    for (int it = 0; it < 4; ++it) {
      const int e = base + it * 256 + tid;   // < 131072
      const int j = e & 7;
      const int lane = (e >> 3) & 63;
      const int m = (e >> 9) & 3;
      const int c = (e >> 11) & 1;
      const int t = e >> 12;
      const int o = m * 16 + (lane & 15);
      const int i = c * 32 + (lane >> 4) * 8 + j;
      wf[e] = f32_to_bf16_rne(w[(size_t)(o * CIN + i) * NTAP + t]);
    }
  }
  __syncthreads();
#pragma unroll
  for (int it = 0; it < 2; ++it) {
    const int pidx = it * 256 + tid;
    const int ll = pidx >> 3;
    const int i8 = (pidx & 7) * 8;
    u16x8 v = {0, 0, 0, 0, 0, 0, 0, 0};
    if (data) {
#pragma unroll
      for (int j = 0; j < 8; ++j) v[j] = f32_to_bf16_rne(tile[ll][i8 + j]);
    }
    *(u16x8*)&xp[(size_t)(b * LPAD + lp0 + ll) * CIN + i8] = v;
  }
}

// ------- main: full-K waves, W in regs, 512-row ring, 7 gap-adapted chunks --------
__global__ __launch_bounds__(256, 2) void sconv_main(const unsigned short* __restrict__ xp,
                                                     const unsigned short* __restrict__ wf,
                                                     float* __restrict__ out) {
  constexpr int TAP[NTAP] = {-512, -256, -128, -96, -64, -48, -32, -24, -16, -12, -8,
                             -6,   -4,   -3,   -2,  -1,  0,   1,   2,   3,   4,  6,
                             8,    12,   16,   24,  32,  48,  64,  96,  128, 256};
  constexpr int NCH = 7;
  constexpr int CS[NCH + 1] = {0, 1, 2, 4, 8, 16, 24, 32};         // chunk tap ranges
  constexpr int SEND[NCH] = {-385, -129, 31, 103, 126, 135, 383};  // staged-through row
  __shared__ alignas(16) char smem[65536];    // ring: 512 rows x 128B

  const int id = blockIdx.x;
  const int b = (id & 7) * 2 + ((id >> 3) & 1);   // XCD k <- batches {2k,2k+1}
  const int l0 = (id >> 4) * 128;                 // 32 l-tiles of 128
  const int lb = l0 + PAD_LO;                     // absolute padded base row (mult of 128)
  const int tid = threadIdx.x;
  const int wv = tid >> 6, lane = tid & 63;
  const int q = lane >> 4, r = lane & 15;
  const int lh = wv;                              // wave: l-quarter (32 l), full K

  const char* xbase = (const char*)xp + ((size_t)b * LPAD + lb) * (CIN * 2);
  const char* wbase = (const char*)wf;

  // stage relative rows [a0, a0+8*ng) into ring; a0 8-aligned.
  // LDS[slot][c'] = G[row][c' ^ (row&7)]
  auto stageB = [&](int a0, int ng) {
    for (int g = wv; g < ng; g += 4) {
      const int ra = a0 + g * 8 + (lane >> 3);
      const int cs = (lane & 7) ^ (ra & 7);
      const int sb = (lb + a0 + g * 8) & 511;     // 8-aligned group, never wraps
      async_copy16(xbase + (ptrdiff_t)ra * 128 + cs * 16, smem + sb * 128);
    }
  };

  bf16x8_s Wreg[2][8], Breg[2][4];   // Wreg[p][m*2+c], Breg[p][n*2+c]
  f32x4 acc[4][2] = {};

  auto loadW = [&](int tt, int p) {               // global, frag-major, coalesced, L1-shared
    const char* src = wbase + tt * 8192 + lane * 16;
#pragma unroll
    for (int m = 0; m < 4; ++m)
#pragma unroll
      for (int c = 0; c < 2; ++c)
        Wreg[p][m * 2 + c] = *(const bf16x8_s*)(src + c * 4096 + m * 1024);
  };
  auto readB = [&](int tt, int p) {
    const int e = (TAP[tt] + r) & 7;              // row&7 for this lane's B rows
#pragma unroll
    for (int n = 0; n < 2; ++n) {
      const int slot = (lb + TAP[tt] + lh * 32 + 16 * n + r) & 511;
#pragma unroll
      for (int c = 0; c < 2; ++c)
        Breg[p][n * 2 + c] = *(const bf16x8_s*)(smem + slot * 128 + (((c * 4 + q) ^ e) << 4));
    }
  };

  // prologue: W(0) to regs; ring rows [-512, -385] (chunk 0's window)
  loadW(0, 0);
  stageB(-512, 16);

#pragma unroll
  for (int i = 0; i < NCH; ++i) {
    __syncthreads();                              // chunk i's rows resident (staged at i-1)
    if (i + 1 < NCH) {                            // stage chunk i+1's delta rows
      const int ds = SEND[i] + 1;
      const int a0 = ds & ~7;                     // align-down: identical-rewrite rows, benign
      stageB(a0, (SEND[i + 1] + 1 - a0 + 7) >> 3);
    }
    __builtin_amdgcn_sched_barrier(0);            // pin staging issue above compute
    readB(CS[i], CS[i] & 1);
#pragma unroll
    for (int t = CS[i]; t < CS[i + 1]; ++t) {
      const int p = t & 1;
      if (t + 1 < NTAP) {
        loadW(t + 1, p ^ 1);                      // global prefetch (no barrier needed)
        if (t + 1 < CS[i + 1]) readB(t + 1, p ^ 1);  // in-chunk B prefetch
      }
      __builtin_amdgcn_sched_barrier(0);          // don't sink prefetch below MFMAs
#pragma unroll
      for (int c = 0; c < 2; ++c)
#pragma unroll
        for (int m = 0; m < 4; ++m)
#pragma unroll
          for (int n = 0; n < 2; ++n)
            acc[m][n] = mfma_16x16x32_bf16(Wreg[p][m * 2 + c], Breg[p][n * 2 + c], acc[m][n], 0);
    }
  }

  // C/D layout (verified): col(l) = lane&15, row(o) = (lane>>4)*4 + reg
#pragma unroll
  for (int m = 0; m < 4; ++m)
#pragma unroll
    for (int n = 0; n < 2; ++n)
#pragma unroll
      for (int d = 0; d < 4; ++d) {
        const int o = 16 * m + 4 * q + d;
        const int l = l0 + lh * 32 + 16 * n + r;
        out[((size_t)b * COUT + o) * LEN + l] = acc[m][n][d];
      }
}

extern "C" void kernel_launch(void* const* d_in, const int* in_sizes, int n_in,
                              void* d_out, int out_size, void* d_ws, size_t ws_size,
                              hipStream_t stream) {
  const float* x = (const float*)d_in[0];        // [16][64][4096]
  const float* w = (const float*)d_in[1];        // [64][64][32]
  float* out = (float*)d_out;                    // [16][64][4096]

  unsigned short* xp = (unsigned short*)d_ws;                    // 16*4864*64 bf16 = 9.96 MB
  unsigned short* wfp = xp + (size_t)B_ * LPAD * CIN;            // 256 KB

  prep_xw<<<dim3(LPAD / 64, B_), 256, 0, stream>>>(x, w, xp, wfp);
  sconv_main<<<dim3(16 * 32), 256, 0, stream>>>(xp, wfp, out);
}